// Round 1
// baseline (673.608 us; speedup 1.0000x reference)
//
#include <hip/hip_runtime.h>

#define T_TOK 4096
#define H_DIM 1024
#define F_DIM 2816
#define E_NUM 8
#define EPSV 1e-5f

typedef unsigned short u16;
typedef __attribute__((ext_vector_type(8))) short bf16x8;
typedef __attribute__((ext_vector_type(4))) float f32x4;

__device__ __forceinline__ u16 f2bf(float f) {
  union { float f; unsigned u; } c; c.f = f;
  unsigned u = c.u;
  return (u16)((u + 0x7FFFu + ((u >> 16) & 1u)) >> 16);
}

// ---------------- Router: RMSNorm + logits + softmax + top2 + gather lists ---
__global__ __launch_bounds__(256) void router_kernel(
    const float* __restrict__ hs, const float* __restrict__ lnw,
    const float* __restrict__ rw, u16* __restrict__ x_h,
    int* __restrict__ cnt, int* __restrict__ list,
    float* __restrict__ wcomb, int* __restrict__ slot) {
  const int wave = threadIdx.x >> 6;
  const int lane = threadIdx.x & 63;
  const int t = blockIdx.x * 4 + wave;
  const float* row = hs + (size_t)t * H_DIM;

  float4 v[4];
  float ss = 0.f;
#pragma unroll
  for (int j = 0; j < 4; ++j) {
    v[j] = ((const float4*)row)[j * 64 + lane];
    ss += v[j].x * v[j].x + v[j].y * v[j].y + v[j].z * v[j].z + v[j].w * v[j].w;
  }
#pragma unroll
  for (int m = 32; m; m >>= 1) ss += __shfl_xor(ss, m, 64);
  const float inv = rsqrtf(ss * (1.0f / H_DIM) + EPSV);

  float lg[E_NUM];
#pragma unroll
  for (int e = 0; e < E_NUM; ++e) lg[e] = 0.f;

#pragma unroll
  for (int j = 0; j < 4; ++j) {
    const int idx = j * 64 + lane;       // float4 index
    const int h0 = idx * 4;
    float4 w4 = ((const float4*)lnw)[idx];
    float xv[4] = {v[j].x * inv * w4.x, v[j].y * inv * w4.y,
                   v[j].z * inv * w4.z, v[j].w * inv * w4.w};
    ushort4 xs;
    xs.x = f2bf(xv[0]); xs.y = f2bf(xv[1]); xs.z = f2bf(xv[2]); xs.w = f2bf(xv[3]);
    ((ushort4*)(x_h + (size_t)t * H_DIM))[idx] = xs;
#pragma unroll
    for (int q = 0; q < 4; ++q) {
      const float* rr = rw + (size_t)(h0 + q) * E_NUM;
      float4 a = ((const float4*)rr)[0];
      float4 b = ((const float4*)rr)[1];
      lg[0] += xv[q] * a.x; lg[1] += xv[q] * a.y;
      lg[2] += xv[q] * a.z; lg[3] += xv[q] * a.w;
      lg[4] += xv[q] * b.x; lg[5] += xv[q] * b.y;
      lg[6] += xv[q] * b.z; lg[7] += xv[q] * b.w;
    }
  }
#pragma unroll
  for (int e = 0; e < E_NUM; ++e)
#pragma unroll
    for (int m = 32; m; m >>= 1) lg[e] += __shfl_xor(lg[e], m, 64);

  if (lane == 0) {
    float mx = lg[0];
#pragma unroll
    for (int e = 1; e < E_NUM; ++e) mx = fmaxf(mx, lg[e]);
    float p[E_NUM], s = 0.f;
#pragma unroll
    for (int e = 0; e < E_NUM; ++e) { p[e] = __expf(lg[e] - mx); s += p[e]; }
    const float invs = 1.0f / s;
    int e1 = 0; float b1 = p[0];
#pragma unroll
    for (int e = 1; e < E_NUM; ++e) if (p[e] > b1) { b1 = p[e]; e1 = e; }
    int e2 = -1; float b2 = -1.f;
#pragma unroll
    for (int e = 0; e < E_NUM; ++e) if (e != e1 && p[e] > b2) { b2 = p[e]; e2 = e; }
    b1 *= invs; b2 *= invs;
    int p1 = atomicAdd(&cnt[e1], 1);
    list[e1 * T_TOK + p1] = t; wcomb[e1 * T_TOK + p1] = b1;
    slot[2 * t] = (e1 << 16) | p1;
    int p2 = atomicAdd(&cnt[e2], 1);
    list[e2 * T_TOK + p2] = t; wcomb[e2 * T_TOK + p2] = b2;
    slot[2 * t + 1] = (e2 << 16) | p2;
  }
}

__global__ void offsets_kernel(const int* __restrict__ cnt, int* __restrict__ offs) {
  if (threadIdx.x == 0) {
    int s = 0;
    for (int e = 0; e < E_NUM; ++e) { offs[e] = s; s += cnt[e]; }
  }
}

// ---------------- fp32 [R][C] -> bf16 [C][R] transpose-convert (per expert z) -
__global__ __launch_bounds__(256) void transpose_cvt(
    const float* __restrict__ in, u16* __restrict__ out, int R, int C) {
  __shared__ float tile[32][33];
  const size_t base = (size_t)blockIdx.z * R * C;
  const int c0 = blockIdx.x * 32, r0 = blockIdx.y * 32;
  const int tx = threadIdx.x, ty = threadIdx.y;
#pragma unroll
  for (int j = 0; j < 32; j += 8)
    tile[ty + j][tx] = in[base + (size_t)(r0 + ty + j) * C + c0 + tx];
  __syncthreads();
#pragma unroll
  for (int j = 0; j < 32; j += 8)
    out[base + (size_t)(c0 + ty + j) * R + r0 + tx] = f2bf(tile[tx][ty + j]);
}

// ---------------- Stage 1: h = silu(X Wg) * (X Wu), gathered rows ------------
__global__ __launch_bounds__(256) void gemm1_kernel(
    const u16* __restrict__ x_h, const u16* __restrict__ wgT,
    const u16* __restrict__ wuT, const int* __restrict__ cnt,
    const int* __restrict__ offs, const int* __restrict__ list,
    u16* __restrict__ hbuf) {
  const int e = blockIdx.z;
  const int n_e = cnt[e];
  const int rt = blockIdx.y;
  if (rt * 128 >= n_e) return;
  const int ft = blockIdx.x;

  __shared__ __align__(16) u16 As[128][72];
  __shared__ __align__(16) u16 Bgs[64][72];
  __shared__ __align__(16) u16 Bus[64][72];
  __shared__ int tok[128];

  const int tid = threadIdx.x;
  if (tid < 128) {
    int r = rt * 128 + tid;
    if (r >= n_e) r = n_e - 1;
    tok[tid] = list[e * T_TOK + r];
  }
  __syncthreads();

  const int wv = tid >> 6, lane = tid & 63;
  const int wm = wv >> 1, wn = wv & 1;
  const int lrow = lane & 15, quad = lane >> 4;

  f32x4 accg[4][2], accu[4][2];
#pragma unroll
  for (int i = 0; i < 4; ++i)
#pragma unroll
    for (int j = 0; j < 2; ++j) {
      accg[i][j] = f32x4{0.f, 0.f, 0.f, 0.f};
      accu[i][j] = f32x4{0.f, 0.f, 0.f, 0.f};
    }

  const size_t wb = ((size_t)e * F_DIM + (size_t)ft * 64) * H_DIM;

  for (int k0 = 0; k0 < H_DIM; k0 += 64) {
#pragma unroll
    for (int i = 0; i < 4; ++i) {
      int c = tid + i * 256;
      int r = c >> 3, kc = (c & 7) << 3;
      *(uint4*)&As[r][kc] = *(const uint4*)(x_h + (size_t)tok[r] * H_DIM + k0 + kc);
    }
#pragma unroll
    for (int i = 0; i < 2; ++i) {
      int c = tid + i * 256;
      int fr = c >> 3, kc = (c & 7) << 3;
      size_t g = wb + (size_t)fr * H_DIM + k0 + kc;
      *(uint4*)&Bgs[fr][kc] = *(const uint4*)(wgT + g);
      *(uint4*)&Bus[fr][kc] = *(const uint4*)(wuT + g);
    }
    __syncthreads();
#pragma unroll
    for (int ks = 0; ks < 2; ++ks) {
      const int kk = ks * 32 + quad * 8;
      bf16x8 a[4], bg[2], bu[2];
#pragma unroll
      for (int tm = 0; tm < 4; ++tm)
        a[tm] = *(const bf16x8*)&As[wm * 64 + tm * 16 + lrow][kk];
#pragma unroll
      for (int tn = 0; tn < 2; ++tn) {
        bg[tn] = *(const bf16x8*)&Bgs[wn * 32 + tn * 16 + lrow][kk];
        bu[tn] = *(const bf16x8*)&Bus[wn * 32 + tn * 16 + lrow][kk];
      }
#pragma unroll
      for (int tm = 0; tm < 4; ++tm)
#pragma unroll
        for (int tn = 0; tn < 2; ++tn) {
          accg[tm][tn] = __builtin_amdgcn_mfma_f32_16x16x32_bf16(a[tm], bg[tn], accg[tm][tn], 0, 0, 0);
          accu[tm][tn] = __builtin_amdgcn_mfma_f32_16x16x32_bf16(a[tm], bu[tn], accu[tm][tn], 0, 0, 0);
        }
    }
    __syncthreads();
  }

  const int oe = offs[e];
#pragma unroll
  for (int tm = 0; tm < 4; ++tm) {
    const int lr0 = wm * 64 + tm * 16 + quad * 4;
#pragma unroll
    for (int rr = 0; rr < 4; ++rr) {
      const int gr = rt * 128 + lr0 + rr;
      if (gr < n_e) {
#pragma unroll
        for (int tn = 0; tn < 2; ++tn) {
          float g = accg[tm][tn][rr];
          float u = accu[tm][tn][rr];
          float hv = g / (1.0f + __expf(-g)) * u;
          int col = ft * 64 + wn * 32 + tn * 16 + lrow;
          hbuf[(size_t)(oe + gr) * F_DIM + col] = f2bf(hv);
        }
      }
    }
  }
}

// ---------------- Stage 2: contrib = combine * (h Wd) ------------------------
__global__ __launch_bounds__(256) void gemm2_kernel(
    const u16* __restrict__ hbuf, const u16* __restrict__ wdT,
    const int* __restrict__ cnt, const int* __restrict__ offs,
    const float* __restrict__ wcomb, float* __restrict__ contrib) {
  const int e = blockIdx.z;
  const int n_e = cnt[e];
  const int rt = blockIdx.y;
  if (rt * 128 >= n_e) return;
  const int nt = blockIdx.x;

  __shared__ __align__(16) u16 As[128][72];
  __shared__ __align__(16) u16 Bs[64][72];
  __shared__ int hrow[128];

  const int tid = threadIdx.x;
  const int oe = offs[e];
  if (tid < 128) {
    int r = rt * 128 + tid;
    if (r >= n_e) r = n_e - 1;
    hrow[tid] = oe + r;
  }
  __syncthreads();

  const int wv = tid >> 6, lane = tid & 63;
  const int wm = wv >> 1, wn = wv & 1;
  const int lrow = lane & 15, quad = lane >> 4;

  f32x4 acc[4][2];
#pragma unroll
  for (int i = 0; i < 4; ++i)
#pragma unroll
    for (int j = 0; j < 2; ++j) acc[i][j] = f32x4{0.f, 0.f, 0.f, 0.f};

  const size_t wb = ((size_t)e * H_DIM + (size_t)nt * 64) * F_DIM;

  for (int k0 = 0; k0 < F_DIM; k0 += 64) {
#pragma unroll
    for (int i = 0; i < 4; ++i) {
      int c = tid + i * 256;
      int r = c >> 3, kc = (c & 7) << 3;
      *(uint4*)&As[r][kc] = *(const uint4*)(hbuf + (size_t)hrow[r] * F_DIM + k0 + kc);
    }
#pragma unroll
    for (int i = 0; i < 2; ++i) {
      int c = tid + i * 256;
      int fr = c >> 3, kc = (c & 7) << 3;
      *(uint4*)&Bs[fr][kc] = *(const uint4*)(wdT + wb + (size_t)fr * F_DIM + k0 + kc);
    }
    __syncthreads();
#pragma unroll
    for (int ks = 0; ks < 2; ++ks) {
      const int kk = ks * 32 + quad * 8;
      bf16x8 a[4], b[2];
#pragma unroll
      for (int tm = 0; tm < 4; ++tm)
        a[tm] = *(const bf16x8*)&As[wm * 64 + tm * 16 + lrow][kk];
#pragma unroll
      for (int tn = 0; tn < 2; ++tn)
        b[tn] = *(const bf16x8*)&Bs[wn * 32 + tn * 16 + lrow][kk];
#pragma unroll
      for (int tm = 0; tm < 4; ++tm)
#pragma unroll
        for (int tn = 0; tn < 2; ++tn)
          acc[tm][tn] = __builtin_amdgcn_mfma_f32_16x16x32_bf16(a[tm], b[tn], acc[tm][tn], 0, 0, 0);
    }
    __syncthreads();
  }

#pragma unroll
  for (int tm = 0; tm < 4; ++tm) {
    const int lr0 = wm * 64 + tm * 16 + quad * 4;
#pragma unroll
    for (int rr = 0; rr < 4; ++rr) {
      const int gr = rt * 128 + lr0 + rr;
      if (gr < n_e) {
        const float cw = wcomb[e * T_TOK + gr];
#pragma unroll
        for (int tn = 0; tn < 2; ++tn) {
          int col = nt * 64 + wn * 32 + tn * 16 + lrow;
          contrib[(size_t)(oe + gr) * H_DIM + col] = acc[tm][tn][rr] * cw;
        }
      }
    }
  }
}

// ---------------- Combine: out[t] = contrib[slot0] + contrib[slot1] ----------
__global__ __launch_bounds__(256) void combine_kernel(
    const float* __restrict__ contrib, const int* __restrict__ offs,
    const int* __restrict__ slot, float* __restrict__ out) {
  const int t = blockIdx.x;
  const int s0 = slot[2 * t], s1 = slot[2 * t + 1];
  const int r0 = offs[s0 >> 16] + (s0 & 0xFFFF);
  const int r1 = offs[s1 >> 16] + (s1 & 0xFFFF);
  float4 a = ((const float4*)(contrib + (size_t)r0 * H_DIM))[threadIdx.x];
  float4 b = ((const float4*)(contrib + (size_t)r1 * H_DIM))[threadIdx.x];
  float4 o = {a.x + b.x, a.y + b.y, a.z + b.z, a.w + b.w};
  ((float4*)(out + (size_t)t * H_DIM))[threadIdx.x] = o;
}

extern "C" void kernel_launch(void* const* d_in, const int* in_sizes, int n_in,
                              void* d_out, int out_size, void* d_ws, size_t ws_size,
                              hipStream_t stream) {
  const float* hs  = (const float*)d_in[0];
  const float* lnw = (const float*)d_in[1];
  const float* rw  = (const float*)d_in[2];
  const float* wg  = (const float*)d_in[3];
  const float* wu  = (const float*)d_in[4];
  const float* wd  = (const float*)d_in[5];
  float* out = (float*)d_out;

  char* p = (char*)d_ws;
  const size_t SZ_XH = (size_t)T_TOK * H_DIM * 2;          // 8 MB
  const size_t SZ_W  = (size_t)E_NUM * F_DIM * H_DIM * 2;  // 46 MB each
  const size_t SZ_HB = (size_t)T_TOK * 2 * F_DIM * 2;      // 46 MB
  const size_t SZ_CT = (size_t)T_TOK * 2 * H_DIM * 4;      // 33.5 MB

  u16* x_h  = (u16*)p;   p += SZ_XH;
  u16* wgT  = (u16*)p;   p += SZ_W;
  u16* wuT  = (u16*)p;   p += SZ_W;
  u16* wdT  = (u16*)p;   p += SZ_W;
  u16* hbuf = (u16*)p;   p += SZ_HB;
  float* contrib = (float*)p; p += SZ_CT;
  int* cnt  = (int*)p;   p += 256;
  int* offs = (int*)p;   p += 256;
  int* list = (int*)p;   p += (size_t)E_NUM * T_TOK * 4;
  float* wcomb = (float*)p; p += (size_t)E_NUM * T_TOK * 4;
  int* slot = (int*)p;   p += (size_t)T_TOK * 2 * 4;

  hipMemsetAsync(cnt, 0, 256, stream);
  router_kernel<<<T_TOK / 4, 256, 0, stream>>>(hs, lnw, rw, x_h, cnt, list, wcomb, slot);
  offsets_kernel<<<1, 64, 0, stream>>>(cnt, offs);
  transpose_cvt<<<dim3(F_DIM / 32, H_DIM / 32, E_NUM), dim3(32, 8), 0, stream>>>(wg, wgT, H_DIM, F_DIM);
  transpose_cvt<<<dim3(F_DIM / 32, H_DIM / 32, E_NUM), dim3(32, 8), 0, stream>>>(wu, wuT, H_DIM, F_DIM);
  transpose_cvt<<<dim3(H_DIM / 32, F_DIM / 32, E_NUM), dim3(32, 8), 0, stream>>>(wd, wdT, F_DIM, H_DIM);
  gemm1_kernel<<<dim3(F_DIM / 64, T_TOK / 128, E_NUM), 256, 0, stream>>>(x_h, wgT, wuT, cnt, offs, list, hbuf);
  gemm2_kernel<<<dim3(H_DIM / 64, T_TOK / 128, E_NUM), 256, 0, stream>>>(hbuf, wdT, cnt, offs, wcomb, contrib);
  combine_kernel<<<T_TOK, 256, 0, stream>>>(contrib, offs, slot, out);
}

// Round 2
// 654.401 us; speedup vs baseline: 1.0294x; 1.0294x over previous
//
#include <hip/hip_runtime.h>

#define T_TOK 4096
#define H_DIM 1024
#define F_DIM 2816
#define E_NUM 8
#define EPSV 1e-5f

typedef unsigned short u16;
typedef __attribute__((ext_vector_type(8))) short bf16x8;
typedef __attribute__((ext_vector_type(4))) float f32x4;

__device__ __forceinline__ u16 f2bf(float f) {
  union { float f; unsigned u; } c; c.f = f;
  unsigned u = c.u;
  return (u16)((u + 0x7FFFu + ((u >> 16) & 1u)) >> 16);
}

// async 16B global->LDS; LDS dest is wave-uniform base + lane*16
__device__ __forceinline__ void llds16(const u16* g, u16* l) {
  __builtin_amdgcn_global_load_lds(
      (const __attribute__((address_space(1))) unsigned int*)g,
      (__attribute__((address_space(3))) unsigned int*)l, 16, 0, 0);
}

// ---------------- Router: RMSNorm + logits + softmax + top2 + gather lists ---
__global__ __launch_bounds__(256) void router_kernel(
    const float* __restrict__ hs, const float* __restrict__ lnw,
    const float* __restrict__ rw, u16* __restrict__ x_h,
    int* __restrict__ cnt, int* __restrict__ list,
    float* __restrict__ wcomb, int* __restrict__ slot) {
  const int wave = threadIdx.x >> 6;
  const int lane = threadIdx.x & 63;
  const int t = blockIdx.x * 4 + wave;
  const float* row = hs + (size_t)t * H_DIM;

  float4 v[4];
  float ss = 0.f;
#pragma unroll
  for (int j = 0; j < 4; ++j) {
    v[j] = ((const float4*)row)[j * 64 + lane];
    ss += v[j].x * v[j].x + v[j].y * v[j].y + v[j].z * v[j].z + v[j].w * v[j].w;
  }
#pragma unroll
  for (int m = 32; m; m >>= 1) ss += __shfl_xor(ss, m, 64);
  const float inv = rsqrtf(ss * (1.0f / H_DIM) + EPSV);

  float lg[E_NUM];
#pragma unroll
  for (int e = 0; e < E_NUM; ++e) lg[e] = 0.f;

#pragma unroll
  for (int j = 0; j < 4; ++j) {
    const int idx = j * 64 + lane;       // float4 index
    const int h0 = idx * 4;
    float4 w4 = ((const float4*)lnw)[idx];
    float xv[4] = {v[j].x * inv * w4.x, v[j].y * inv * w4.y,
                   v[j].z * inv * w4.z, v[j].w * inv * w4.w};
    ushort4 xs;
    xs.x = f2bf(xv[0]); xs.y = f2bf(xv[1]); xs.z = f2bf(xv[2]); xs.w = f2bf(xv[3]);
    ((ushort4*)(x_h + (size_t)t * H_DIM))[idx] = xs;
#pragma unroll
    for (int q = 0; q < 4; ++q) {
      const float* rr = rw + (size_t)(h0 + q) * E_NUM;
      float4 a = ((const float4*)rr)[0];
      float4 b = ((const float4*)rr)[1];
      lg[0] += xv[q] * a.x; lg[1] += xv[q] * a.y;
      lg[2] += xv[q] * a.z; lg[3] += xv[q] * a.w;
      lg[4] += xv[q] * b.x; lg[5] += xv[q] * b.y;
      lg[6] += xv[q] * b.z; lg[7] += xv[q] * b.w;
    }
  }
#pragma unroll
  for (int e = 0; e < E_NUM; ++e)
#pragma unroll
    for (int m = 32; m; m >>= 1) lg[e] += __shfl_xor(lg[e], m, 64);

  if (lane == 0) {
    float mx = lg[0];
#pragma unroll
    for (int e = 1; e < E_NUM; ++e) mx = fmaxf(mx, lg[e]);
    float p[E_NUM], s = 0.f;
#pragma unroll
    for (int e = 0; e < E_NUM; ++e) { p[e] = __expf(lg[e] - mx); s += p[e]; }
    const float invs = 1.0f / s;
    int e1 = 0; float b1 = p[0];
#pragma unroll
    for (int e = 1; e < E_NUM; ++e) if (p[e] > b1) { b1 = p[e]; e1 = e; }
    int e2 = -1; float b2 = -1.f;
#pragma unroll
    for (int e = 0; e < E_NUM; ++e) if (e != e1 && p[e] > b2) { b2 = p[e]; e2 = e; }
    b1 *= invs; b2 *= invs;
    int p1 = atomicAdd(&cnt[e1], 1);
    list[e1 * T_TOK + p1] = t; wcomb[e1 * T_TOK + p1] = b1;
    slot[2 * t] = (e1 << 16) | p1;
    int p2 = atomicAdd(&cnt[e2], 1);
    list[e2 * T_TOK + p2] = t; wcomb[e2 * T_TOK + p2] = b2;
    slot[2 * t + 1] = (e2 << 16) | p2;
  }
}

__global__ void offsets_kernel(const int* __restrict__ cnt, int* __restrict__ offs) {
  if (threadIdx.x == 0) {
    int s = 0;
    for (int e = 0; e < E_NUM; ++e) { offs[e] = s; s += cnt[e]; }
  }
}

// ---------------- fp32 [R][C] -> bf16 [C][R] transpose-convert (per expert z) -
__global__ __launch_bounds__(256) void transpose_cvt(
    const float* __restrict__ in, u16* __restrict__ out, int R, int C) {
  __shared__ float tile[32][33];
  const size_t base = (size_t)blockIdx.z * R * C;
  const int c0 = blockIdx.x * 32, r0 = blockIdx.y * 32;
  const int tx = threadIdx.x, ty = threadIdx.y;
#pragma unroll
  for (int j = 0; j < 32; j += 8)
    tile[ty + j][tx] = in[base + (size_t)(r0 + ty + j) * C + c0 + tx];
  __syncthreads();
#pragma unroll
  for (int j = 0; j < 32; j += 8)
    out[base + (size_t)(c0 + ty + j) * R + r0 + tx] = f2bf(tile[tx][ty + j]);
}

// ---------------- Stage 1: h = silu(X Wg) * (X Wu), gathered rows ------------
// LDS layout: row-major [row][64] u16, 16B chunk c of row r stored at phys
// chunk c^(r&7)  -> global_load_lds staging is contiguous, ds_read_b128 2-way.
__global__ __launch_bounds__(256) void gemm1_kernel(
    const u16* __restrict__ x_h, const u16* __restrict__ wgT,
    const u16* __restrict__ wuT, const int* __restrict__ cnt,
    const int* __restrict__ offs, const int* __restrict__ list,
    u16* __restrict__ hbuf) {
  const int e = blockIdx.z;
  const int n_e = cnt[e];
  const int rt = blockIdx.y;
  if (rt * 128 >= n_e) return;
  const int ft = blockIdx.x;

  __shared__ __align__(16) u16 As[128 * 64];
  __shared__ __align__(16) u16 Bgs[64 * 64];
  __shared__ __align__(16) u16 Bus[64 * 64];
  __shared__ int tok[128];

  const int tid = threadIdx.x;
  if (tid < 128) {
    int r = rt * 128 + tid;
    if (r >= n_e) r = n_e - 1;
    tok[tid] = list[e * T_TOK + r];
  }
  __syncthreads();

  const int wv = tid >> 6, lane = tid & 63;
  const int wm = wv >> 1, wn = wv & 1;
  const int lrow = lane & 15, quad = lane >> 4;
  const int srow = lane >> 3, schunk = lane & 7;   // staging: 8 rows x 8 chunks

  // staging global pointers (advance by 64 per k-step)
  const u16* agp[4];
#pragma unroll
  for (int i = 0; i < 4; ++i) {
    int r = wv * 32 + i * 8 + srow;
    agp[i] = x_h + (size_t)tok[r] * H_DIM + ((schunk ^ (r & 7)) << 3);
  }
  const size_t wb = ((size_t)e * F_DIM + (size_t)ft * 64) * H_DIM;
  const u16* bgp[2]; const u16* bup[2];
#pragma unroll
  for (int i = 0; i < 2; ++i) {
    int r = wv * 16 + i * 8 + srow;
    size_t g = wb + (size_t)r * H_DIM + ((schunk ^ (r & 7)) << 3);
    bgp[i] = wgT + g;
    bup[i] = wuT + g;
  }

  // loop-invariant LDS fragment pointers (swizzled)
  const u16* aptr[4][2]; const u16* bgptr[2][2]; const u16* buptr[2][2];
#pragma unroll
  for (int tm = 0; tm < 4; ++tm) {
    int row = wm * 64 + tm * 16 + lrow;
#pragma unroll
    for (int ks = 0; ks < 2; ++ks)
      aptr[tm][ks] = &As[row * 64 + (((ks * 4 + quad) ^ (row & 7)) << 3)];
  }
#pragma unroll
  for (int tn = 0; tn < 2; ++tn) {
    int row = wn * 32 + tn * 16 + lrow;
#pragma unroll
    for (int ks = 0; ks < 2; ++ks) {
      int off = row * 64 + (((ks * 4 + quad) ^ (row & 7)) << 3);
      bgptr[tn][ks] = &Bgs[off];
      buptr[tn][ks] = &Bus[off];
    }
  }

  f32x4 accg[4][2], accu[4][2];
#pragma unroll
  for (int i = 0; i < 4; ++i)
#pragma unroll
    for (int j = 0; j < 2; ++j) {
      accg[i][j] = f32x4{0.f, 0.f, 0.f, 0.f};
      accu[i][j] = f32x4{0.f, 0.f, 0.f, 0.f};
    }

  for (int k0 = 0; k0 < H_DIM; k0 += 64) {
#pragma unroll
    for (int i = 0; i < 4; ++i)
      llds16(agp[i] + k0, &As[(wv * 32 + i * 8) * 64]);
#pragma unroll
    for (int i = 0; i < 2; ++i) {
      llds16(bgp[i] + k0, &Bgs[(wv * 16 + i * 8) * 64]);
      llds16(bup[i] + k0, &Bus[(wv * 16 + i * 8) * 64]);
    }
    __syncthreads();
#pragma unroll
    for (int ks = 0; ks < 2; ++ks) {
      bf16x8 a[4], bg[2], bu[2];
#pragma unroll
      for (int tm = 0; tm < 4; ++tm) a[tm] = *(const bf16x8*)aptr[tm][ks];
#pragma unroll
      for (int tn = 0; tn < 2; ++tn) {
        bg[tn] = *(const bf16x8*)bgptr[tn][ks];
        bu[tn] = *(const bf16x8*)buptr[tn][ks];
      }
#pragma unroll
      for (int tm = 0; tm < 4; ++tm)
#pragma unroll
        for (int tn = 0; tn < 2; ++tn) {
          accg[tm][tn] = __builtin_amdgcn_mfma_f32_16x16x32_bf16(a[tm], bg[tn], accg[tm][tn], 0, 0, 0);
          accu[tm][tn] = __builtin_amdgcn_mfma_f32_16x16x32_bf16(a[tm], bu[tn], accu[tm][tn], 0, 0, 0);
        }
    }
    __syncthreads();
  }

  const int oe = offs[e];
#pragma unroll
  for (int tm = 0; tm < 4; ++tm) {
    const int lr0 = wm * 64 + tm * 16 + quad * 4;
#pragma unroll
    for (int rr = 0; rr < 4; ++rr) {
      const int gr = rt * 128 + lr0 + rr;
      if (gr < n_e) {
#pragma unroll
        for (int tn = 0; tn < 2; ++tn) {
          float g = accg[tm][tn][rr];
          float u = accu[tm][tn][rr];
          float hv = g / (1.0f + __expf(-g)) * u;
          int col = ft * 64 + wn * 32 + tn * 16 + lrow;
          hbuf[(size_t)(oe + gr) * F_DIM + col] = f2bf(hv);
        }
      }
    }
  }
}

// ---------------- Stage 2: contrib = combine * (h Wd), 128x128 tile ----------
__global__ __launch_bounds__(256) void gemm2_kernel(
    const u16* __restrict__ hbuf, const u16* __restrict__ wdT,
    const int* __restrict__ cnt, const int* __restrict__ offs,
    const float* __restrict__ wcomb, float* __restrict__ contrib) {
  const int e = blockIdx.z;
  const int n_e = cnt[e];
  const int rt = blockIdx.y;
  if (rt * 128 >= n_e) return;
  const int nt = blockIdx.x;

  __shared__ __align__(16) u16 As[128 * 64];
  __shared__ __align__(16) u16 Bs[128 * 64];
  __shared__ int hrow[128];

  const int tid = threadIdx.x;
  const int oe = offs[e];
  if (tid < 128) {
    int r = rt * 128 + tid;
    if (r >= n_e) r = n_e - 1;
    hrow[tid] = oe + r;
  }
  __syncthreads();

  const int wv = tid >> 6, lane = tid & 63;
  const int wm = wv >> 1, wn = wv & 1;
  const int lrow = lane & 15, quad = lane >> 4;
  const int srow = lane >> 3, schunk = lane & 7;

  const u16* agp[4];
#pragma unroll
  for (int i = 0; i < 4; ++i) {
    int r = wv * 32 + i * 8 + srow;
    agp[i] = hbuf + (size_t)hrow[r] * F_DIM + ((schunk ^ (r & 7)) << 3);
  }
  const size_t wb = ((size_t)e * H_DIM + (size_t)nt * 128) * F_DIM;
  const u16* bgp[4];
#pragma unroll
  for (int i = 0; i < 4; ++i) {
    int r = wv * 32 + i * 8 + srow;
    bgp[i] = wdT + wb + (size_t)r * F_DIM + ((schunk ^ (r & 7)) << 3);
  }

  const u16* aptr[4][2]; const u16* bptr[4][2];
#pragma unroll
  for (int tm = 0; tm < 4; ++tm) {
    int row = wm * 64 + tm * 16 + lrow;
#pragma unroll
    for (int ks = 0; ks < 2; ++ks)
      aptr[tm][ks] = &As[row * 64 + (((ks * 4 + quad) ^ (row & 7)) << 3)];
  }
#pragma unroll
  for (int tn = 0; tn < 4; ++tn) {
    int row = wn * 64 + tn * 16 + lrow;
#pragma unroll
    for (int ks = 0; ks < 2; ++ks)
      bptr[tn][ks] = &Bs[row * 64 + (((ks * 4 + quad) ^ (row & 7)) << 3)];
  }

  f32x4 acc[4][4];
#pragma unroll
  for (int i = 0; i < 4; ++i)
#pragma unroll
    for (int j = 0; j < 4; ++j) acc[i][j] = f32x4{0.f, 0.f, 0.f, 0.f};

  for (int k0 = 0; k0 < F_DIM; k0 += 64) {
#pragma unroll
    for (int i = 0; i < 4; ++i) {
      llds16(agp[i] + k0, &As[(wv * 32 + i * 8) * 64]);
      llds16(bgp[i] + k0, &Bs[(wv * 32 + i * 8) * 64]);
    }
    __syncthreads();
#pragma unroll
    for (int ks = 0; ks < 2; ++ks) {
      bf16x8 a[4], b[4];
#pragma unroll
      for (int tm = 0; tm < 4; ++tm) a[tm] = *(const bf16x8*)aptr[tm][ks];
#pragma unroll
      for (int tn = 0; tn < 4; ++tn) b[tn] = *(const bf16x8*)bptr[tn][ks];
#pragma unroll
      for (int tm = 0; tm < 4; ++tm)
#pragma unroll
        for (int tn = 0; tn < 4; ++tn)
          acc[tm][tn] = __builtin_amdgcn_mfma_f32_16x16x32_bf16(a[tm], b[tn], acc[tm][tn], 0, 0, 0);
    }
    __syncthreads();
  }

#pragma unroll
  for (int tm = 0; tm < 4; ++tm) {
    const int lr0 = wm * 64 + tm * 16 + quad * 4;
#pragma unroll
    for (int rr = 0; rr < 4; ++rr) {
      const int gr = rt * 128 + lr0 + rr;
      if (gr < n_e) {
        const float cw = wcomb[e * T_TOK + gr];
#pragma unroll
        for (int tn = 0; tn < 4; ++tn) {
          int col = nt * 128 + wn * 64 + tn * 16 + lrow;
          contrib[(size_t)(oe + gr) * H_DIM + col] = acc[tm][tn][rr] * cw;
        }
      }
    }
  }
}

// ---------------- Combine: out[t] = contrib[slot0] + contrib[slot1] ----------
__global__ __launch_bounds__(256) void combine_kernel(
    const float* __restrict__ contrib, const int* __restrict__ offs,
    const int* __restrict__ slot, float* __restrict__ out) {
  const int t = blockIdx.x;
  const int s0 = slot[2 * t], s1 = slot[2 * t + 1];
  const int r0 = offs[s0 >> 16] + (s0 & 0xFFFF);
  const int r1 = offs[s1 >> 16] + (s1 & 0xFFFF);
  float4 a = ((const float4*)(contrib + (size_t)r0 * H_DIM))[threadIdx.x];
  float4 b = ((const float4*)(contrib + (size_t)r1 * H_DIM))[threadIdx.x];
  float4 o = {a.x + b.x, a.y + b.y, a.z + b.z, a.w + b.w};
  ((float4*)(out + (size_t)t * H_DIM))[threadIdx.x] = o;
}

extern "C" void kernel_launch(void* const* d_in, const int* in_sizes, int n_in,
                              void* d_out, int out_size, void* d_ws, size_t ws_size,
                              hipStream_t stream) {
  const float* hs  = (const float*)d_in[0];
  const float* lnw = (const float*)d_in[1];
  const float* rw  = (const float*)d_in[2];
  const float* wg  = (const float*)d_in[3];
  const float* wu  = (const float*)d_in[4];
  const float* wd  = (const float*)d_in[5];
  float* out = (float*)d_out;

  char* p = (char*)d_ws;
  const size_t SZ_XH = (size_t)T_TOK * H_DIM * 2;          // 8 MB
  const size_t SZ_W  = (size_t)E_NUM * F_DIM * H_DIM * 2;  // 46 MB each
  const size_t SZ_HB = (size_t)T_TOK * 2 * F_DIM * 2;      // 46 MB
  const size_t SZ_CT = (size_t)T_TOK * 2 * H_DIM * 4;      // 33.5 MB

  u16* x_h  = (u16*)p;   p += SZ_XH;
  u16* wgT  = (u16*)p;   p += SZ_W;
  u16* wuT  = (u16*)p;   p += SZ_W;
  u16* wdT  = (u16*)p;   p += SZ_W;
  u16* hbuf = (u16*)p;   p += SZ_HB;
  float* contrib = (float*)p; p += SZ_CT;
  int* cnt  = (int*)p;   p += 256;
  int* offs = (int*)p;   p += 256;
  int* list = (int*)p;   p += (size_t)E_NUM * T_TOK * 4;
  float* wcomb = (float*)p; p += (size_t)E_NUM * T_TOK * 4;
  int* slot = (int*)p;   p += (size_t)T_TOK * 2 * 4;

  hipMemsetAsync(cnt, 0, 256, stream);
  router_kernel<<<T_TOK / 4, 256, 0, stream>>>(hs, lnw, rw, x_h, cnt, list, wcomb, slot);
  offsets_kernel<<<1, 64, 0, stream>>>(cnt, offs);
  transpose_cvt<<<dim3(F_DIM / 32, H_DIM / 32, E_NUM), dim3(32, 8), 0, stream>>>(wg, wgT, H_DIM, F_DIM);
  transpose_cvt<<<dim3(F_DIM / 32, H_DIM / 32, E_NUM), dim3(32, 8), 0, stream>>>(wu, wuT, H_DIM, F_DIM);
  transpose_cvt<<<dim3(H_DIM / 32, F_DIM / 32, E_NUM), dim3(32, 8), 0, stream>>>(wd, wdT, F_DIM, H_DIM);
  gemm1_kernel<<<dim3(F_DIM / 64, T_TOK / 128, E_NUM), 256, 0, stream>>>(x_h, wgT, wuT, cnt, offs, list, hbuf);
  gemm2_kernel<<<dim3(H_DIM / 128, T_TOK / 128, E_NUM), 256, 0, stream>>>(hbuf, wdT, cnt, offs, wcomb, contrib);
  combine_kernel<<<T_TOK, 256, 0, stream>>>(contrib, offs, slot, out);
}